// Round 1
// baseline (491.358 us; speedup 1.0000x reference)
//
#include <hip/hip_runtime.h>
#include <math.h>

#define BIGNEG (-1000000000.0f)

// Problem-fixed sizes: b=4, N1=512, d=64, C1=32, K=32, C=33, N=513
// ws float offsets
constexpr int OFF_MINV   = 0;        // 64*64 = 4096
constexpr int OFF_LOGDET = 4096;     // 1
constexpr int OFF_Q      = 4100;     // 32*64 = 2048   q[c][t] = Minv @ mean_c
constexpr int OFF_S      = 6148;     // 32             s[c] = mean_c . q[c]
constexpr int OFF_TRANS  = 6180;     // 33*33 = 1089
constexpr int OFF_LENAUG = 7269;     // 32*33 = 1056
constexpr int OFF_INITA  = 8325;     // 33
constexpr int OFF_EOS    = 8358;     // 513
constexpr int OFF_EMLAST = 8871;     // 33
constexpr int OFF_EMT    = 8904;     // 4*32*512 = 65536  (em transposed: [b][c][t])

__device__ __forceinline__ float rl(float x, int l) {
    return __int_as_float(__builtin_amdgcn_readlane(__float_as_int(x), l));
}

// Single-wave register-resident Gauss-Jordan: lane = row, 64+64 cols in VGPRs.
// Pivot-row broadcast via v_readlane (VALU pipe) -> zero LDS traffic, zero
// barriers in the 64-pivot loop (vs 64 __syncthreads + ~380 LDS instrs/pivot).
__global__ __launch_bounds__(256) void setup_kernel(
    const float* __restrict__ cov, const float* __restrict__ means,
    const float* __restrict__ plr, const float* __restrict__ tlogits,
    const float* __restrict__ ilogits, const int* __restrict__ lengths,
    float* __restrict__ ws)
{
    __shared__ float A[64][65];      // staging for cov, then holds scaled Minv
    __shared__ float lse_t[32];
    __shared__ float ilse;
    const int tid = threadIdx.x;

    // coalesced cov -> LDS
    for (int idx = tid; idx < 64 * 64; idx += 256)
        A[idx >> 6][idx & 63] = cov[idx];
    __syncthreads();

    if (tid < 64) {                  // wave 0 only: GJ entirely in registers
        const int lane = tid;
        float L[64], R[64];
#pragma unroll
        for (int c = 0; c < 64; ++c) {
            L[c] = A[lane][c];
            R[c] = (lane == c) ? 1.f : 0.f;
        }
        float curcol = L[0];         // column p of left half, per lane
        float myd = 1.f;             // this row's pivot value d_r
#pragma unroll 1
        for (int p = 0; p < 64; ++p) {
            const float d = rl(curcol, p);          // A[p][p]
            const float invd = 1.f / d;
            const float f = (lane == p) ? 0.f : curcol * invd;
            myd = (lane == p) ? d : myd;
            float nextcol = 0.f;
#pragma unroll
            for (int c = 0; c < 64; ++c) {
                const float piv = rl(L[c], p);      // pivot-row broadcast
                L[c] = fmaf(-f, piv, L[c]);
                if (c == p + 1) nextcol = L[c];     // uniform select: track next pivot col
            }
#pragma unroll
            for (int c = 0; c < 64; ++c) {
                const float piv = rl(R[c], p);
                R[c] = fmaf(-f, piv, R[c]);
            }
            curcol = nextcol;
        }
        // after 64 pivots: right half = diag(d_r) * Minv  ->  Minv = R / d_r
        const float rdv = 1.f / myd;
#pragma unroll
        for (int c = 0; c < 64; ++c) A[lane][c] = R[c] * rdv;
        // logdet = sum_r log d_r via butterfly reduce
        float lg = logf(myd);
        for (int m = 32; m >= 1; m >>= 1) lg += __shfl_xor(lg, m, 64);
        if (lane == 0) ws[OFF_LOGDET] = lg;
    }
    __syncthreads();

    // Minv -> ws (coalesced), A now holds the final (scaled) inverse
    for (int idx = tid; idx < 4096; idx += 256)
        ws[OFF_MINV + idx] = A[idx >> 6][idx & 63];
    // q[c][t] = sum_e Minv[t][e] * means[c][e]
    for (int idx = tid; idx < 32 * 64; idx += 256) {
        const int c = idx >> 6, t = idx & 63;
        float acc = 0.f;
        for (int e = 0; e < 64; ++e) acc += A[t][e] * means[c * 64 + e];
        ws[OFF_Q + idx] = acc;
    }
    __syncthreads();
    if (tid < 32) {
        const int c = tid;
        float acc = 0.f;
        for (int t = 0; t < 64; ++t) acc += means[c * 64 + t] * ws[OFF_Q + c * 64 + t];
        ws[OFF_S + c] = acc;
    }
    // column-wise logsumexp of masked transition logits
    if (tid < 32) {
        const int j = tid;
        float mx = -INFINITY;
        for (int i = 0; i < 32; ++i) {
            const float x = (i == j) ? BIGNEG : tlogits[i * 32 + j];
            mx = fmaxf(mx, x);
        }
        float sum = 0.f;
        for (int i = 0; i < 32; ++i) {
            const float x = (i == j) ? BIGNEG : tlogits[i * 32 + j];
            sum += expf(x - mx);
        }
        lse_t[j] = mx + logf(sum);
    }
    if (tid == 0) {
        float mx = -INFINITY;
        for (int i = 0; i < 32; ++i) mx = fmaxf(mx, ilogits[i]);
        float sum = 0.f;
        for (int i = 0; i < 32; ++i) sum += expf(ilogits[i] - mx);
        ilse = mx + logf(sum);
    }
    __syncthreads();
    // trans_aug (33x33)
    for (int idx = tid; idx < 1089; idx += 256) {
        const int i = idx / 33, j = idx - i * 33;
        float v;
        if (i == 32) v = 0.f;
        else if (j == 32) v = BIGNEG;
        else if (i == j) v = BIGNEG - lse_t[j];
        else v = tlogits[i * 32 + j] - lse_t[j];
        ws[OFF_TRANS + idx] = v;
    }
    if (tid < 33) ws[OFF_INITA + tid] = (tid < 32) ? (ilogits[tid] - ilse) : BIGNEG;
    // len_aug (32x33)
    for (int idx = tid; idx < 32 * 33; idx += 256) {
        const int k = idx / 33, j = idx - k * 33;
        float v;
        if (j < 32) v = (float)k * plr[j] - expf(plr[j]) - lgammaf((float)k + 1.f);
        else        v = (k == 1) ? 0.f : BIGNEG;
        ws[OFF_LENAUG + idx] = v;
    }
    // eos column (shared across batch)
    const int l0 = lengths[0], l1 = lengths[1], l2 = lengths[2], l3 = lengths[3];
    for (int t = tid; t < 513; t += 256) {
        const bool any = (l0 == t) | (l1 == t) | (l2 == t) | (l3 == t);
        ws[OFF_EOS + t] = any ? 0.f : BIGNEG;
    }
    // em_last[i] = em_aug[:, 512, i]
    if (tid < 33) {
        float v = BIGNEG;
        if (tid == 32) {
            const bool any = (l0 == 512) | (l1 == 512) | (l2 == 512) | (l3 == 512);
            v = any ? 0.f : BIGNEG;
        }
        ws[OFF_EMLAST + tid] = v;
    }
}

// em_t[b][c][n] = -0.5*(f'Minv f - 2 f'q_c + s_c + d*log(2pi) + logdet); one wave per (b,n)
__global__ __launch_bounds__(256) void em_kernel(
    const float* __restrict__ features, float* __restrict__ ws)
{
    __shared__ float sM[64][65];
    __shared__ float sq[32][65];
    __shared__ float sf[4][64];
    __shared__ float ss[32];
    const int tid = threadIdx.x;
    for (int idx = tid; idx < 4096; idx += 256) sM[idx >> 6][idx & 63] = ws[OFF_MINV + idx];
    for (int idx = tid; idx < 2048; idx += 256) sq[idx >> 6][idx & 63] = ws[OFF_Q + idx];
    if (tid < 32) ss[tid] = ws[OFF_S + tid];
    const float logdet = ws[OFF_LOGDET];
    const int w = tid >> 6, lane = tid & 63;
    const int p = blockIdx.x * 4 + w;       // (b,n) pair index, b = p>>9, n = p&511
    sf[w][lane] = features[p * 64 + lane];
    __syncthreads();

    float u = 0.f;
    for (int e = 0; e < 64; ++e) u += sM[lane][e] * sf[w][e];
    float a = sf[w][lane] * u;
    for (int m = 32; m >= 1; m >>= 1) a += __shfl_xor(a, m, 64);

    const int c = lane >> 1, h = lane & 1;
    float pd = 0.f;
    const int eb = h * 32;
    for (int e = 0; e < 32; ++e) pd += sf[w][eb + e] * sq[c][eb + e];
    pd += __shfl_xor(pd, 1, 64);

    const float em = -0.5f * (a - 2.f * pd + ss[c] + 64.f * 1.8378770664093453f + logdet);
    const int b = p >> 9, n = p & 511;
    if (h == 0) ws[OFF_EMT + (b * 32 + c) * 512 + n] = em;
}

// scores[b,t,k,i,j] = trans[i,j] + len_aug[k,j] + win[b,t,k,j] + t0*init[j] + last*em_last[i]
// Window sums computed locally from em_t (<=31-element prefix per column) --
// replaces the separate csum kernel (132 lone waves + a launch/drain gap).
__global__ __launch_bounds__(256) void score_kernel(
    const float* __restrict__ ws, const int* __restrict__ lengths,
    float* __restrict__ out)
{
    __shared__ float sT[1089];
    __shared__ float sA[32 * 33];
    const int tid = threadIdx.x;
    const int blk = blockIdx.x;
    const int b = blk >> 9, t = blk & 511;

    for (int idx = tid; idx < 1089; idx += 256) sT[idx] = ws[OFF_TRANS + idx];
    const bool t0 = (t == 0);
    for (int idx = tid; idx < 1056; idx += 256) {
        const int j = idx % 33;
        float v = ws[OFF_LENAUG + idx];
        if (t0) v += ws[OFF_INITA + j];
        sA[idx] = v;            // k=0 row stays window-free (empty window)
    }
    __syncthreads();

    // per-column running window sums: win[k][j] = sum_{u=t}^{min(t+k,513)-1} em_aug[b][u][j]
    if (tid < 33) {
        const int j = tid;
        const int len = lengths[b];
        const float* emc = ws + OFF_EMT + (b * 32 + j) * 512;   // deref'd only for j<32
        const float* eos = ws + OFF_EOS;
        float vals[31];
#pragma unroll
        for (int i = 0; i < 31; ++i) {          // u = t+i, prefetched (independent loads)
            const int u = t + i;
            float x;
            if (u > 512)      x = 0.f;          // window clipped at N=513
            else if (j == 32) x = eos[u];
            else              x = (u < len) ? emc[u] : BIGNEG;
            vals[i] = x;
        }
        float run = 0.f;
#pragma unroll
        for (int k = 1; k < 32; ++k) { run += vals[k - 1]; sA[k * 33 + j] += run; }
    }

    float tv[5], el[5];
    int jj[5];
    const float* emlast = ws + OFF_EMLAST;
#pragma unroll
    for (int m = 0; m < 5; ++m) {
        const int idx = tid + 256 * m;
        if (idx < 1089) {
            const int i = idx / 33;
            jj[m] = idx - i * 33;
            tv[m] = sT[idx];
            el[m] = emlast[i];
        } else { jj[m] = 0; tv[m] = 0.f; el[m] = 0.f; }
    }
    __syncthreads();

    const bool has5 = (tid < 65);
    const int kk = 512 - t;   // the unique k>=1 receiving em_last (if < 32)
    float* ob = out + (size_t)(b * 512 + t) * 32 * 1089;
    for (int k = 0; k < 32; ++k) {
        const float add = (k == kk) ? 1.f : 0.f;
        const float* Ak = sA + k * 33;
        float* op = ob + (size_t)k * 1089;
#pragma unroll
        for (int m = 0; m < 4; ++m)
            __builtin_nontemporal_store(tv[m] + Ak[jj[m]] + add * el[m], op + tid + 256 * m);
        if (has5)
            __builtin_nontemporal_store(tv[4] + Ak[jj[4]] + add * el[4], op + tid + 1024);
    }
}

extern "C" void kernel_launch(void* const* d_in, const int* in_sizes, int n_in,
                              void* d_out, int out_size, void* d_ws, size_t ws_size,
                              hipStream_t stream) {
    (void)in_sizes; (void)n_in; (void)out_size; (void)ws_size;
    const float* features = (const float*)d_in[0];   // (4,512,64)
    const int*   lengths  = (const int*)d_in[1];     // (4,)
    const float* means    = (const float*)d_in[2];   // (32,64)
    const float* cov      = (const float*)d_in[3];   // (64,64)
    const float* plr      = (const float*)d_in[4];   // (32,)
    const float* tlog     = (const float*)d_in[5];   // (32,32)
    const float* ilog     = (const float*)d_in[6];   // (32,)
    float* ws  = (float*)d_ws;
    float* out = (float*)d_out;

    setup_kernel<<<1, 256, 0, stream>>>(cov, means, plr, tlog, ilog, lengths, ws);
    em_kernel<<<512, 256, 0, stream>>>(features, ws);
    score_kernel<<<2048, 256, 0, stream>>>(ws, lengths, out);
}